// Round 10
// baseline (105.982 us; speedup 1.0000x reference)
//
#include <hip/hip_runtime.h>

// VQ nearest-neighbor via f16-split MFMA. N=65536 queries, DIM=64, K=1024.
// v = dot(z,c) - csq[k]/2; argmax_k v  ==  argmin_k ||z-c||^2.
//
// Round-15. Ledger across 8 variants: per-CU VMEM read throughput pinned at
// 31-38 GB/s (~13-16 B/cy) while MfmaUtil sits 19-21% -- independent of
// occupancy, chain depth, prefetch depth, sweep order. Diagnosis: bound by
// per-CU vector-memory throughput (each wave privately streams the 400 KB
// codebook; 419 MB of VMEM total). Fix: read each tile ONCE per CU and
// share via LDS (separate 128 B/cy pipe).
//  * Block = 512 thr = 8 waves = 4 query-groups (64 q) x 2 K-halves.
//    Grid 256 = 1 block/CU. Per-CU global bytes/iter: 51.2 -> 12.5 KB.
//  * Per iter: 14 stage-units (2 streams x {c,6 frags}) spread over the 8
//    waves (<=2 each). Global->reg issued at loop TOP, ds_write after the
//    compute phase (T14: ~900 cy of MFMA covers the load), one barrier per
//    iteration, LDS double-buffer (2 streams x 2 bufs x 6400 B).
//  * Compute reads operands via ds_read_b128; MFMA chains + epilogue
//    identical to round 9 (two independent 3-chains, exact tie-breaks).
//
// Carried: 2^11-scaled scoring SA = csq' + al0'*bh_u0 + ah0*bl0' + ah0*bh_s0,
// SB = al1'*bh_u1 + ah1*bl1' + ah1*bh_s1, v = SA+SB (bh_s = ch*2048 exact
// f16 exponent shift, bl' = cl*2048, al' = zl*2048, csq' = -1024*csq).

typedef _Float16 half8 __attribute__((ext_vector_type(8)));
typedef float float4v __attribute__((ext_vector_type(4)));

constexpr int KCODES = 1024;
constexpr int DIM = 64;

// Tile layout in d_ws (64 tiles of 16 codes each), TILE_BYTES = 6400:
//   byte 0..255              : 64 f32, slot (quad*16+m) = -2048*csq[T*16+m]/2
//   byte 256 + kt*3072 + f*1024 + (quad*16+m)*16 : half8 frag
//     f=0: bh_u (ch, f16)   f=1: bh_s (ch*2048)   f=2: bl' (cl*2048)
//   dim = kt*32 + quad*8 + j
constexpr int TILE_BYTES = 6400;

__global__ __launch_bounds__(256) void prep_kernel(
    const float* __restrict__ cb, char* __restrict__ cbf) {
  const int g = blockIdx.x * 256 + threadIdx.x;  // grid 32 x 256 = 8192
  const int k = g >> 3, sub = g & 7;
  const int kt = sub >> 2, quad = sub & 3;
  const int T = k >> 4, m = k & 15;

  const float* src = cb + (size_t)k * DIM + kt * 32 + quad * 8;
  const float4 p0 = ((const float4*)src)[0];
  const float4 p1 = ((const float4*)src)[1];
  const float x[8] = {p0.x, p0.y, p0.z, p0.w, p1.x, p1.y, p1.z, p1.w};

  half8 hu, hs, l8;
  float s = 0.f;
#pragma unroll
  for (int j = 0; j < 8; ++j) {
    s = fmaf(x[j], x[j], s);
    const _Float16 h = (_Float16)x[j];
    hu[j] = h;
    hs[j] = (_Float16)((float)h * 2048.0f);          // exact exponent shift
    l8[j] = (_Float16)((x[j] - (float)h) * 2048.0f); // verified lo scaling
  }
  // csq summed over the 8 sub-threads of this code (xor 1/2/4 stays in-wave).
  s += __shfl_xor(s, 1);
  s += __shfl_xor(s, 2);
  s += __shfl_xor(s, 4);

  char* tbase = cbf + (size_t)T * TILE_BYTES;
  // csq' = 2^11 * (-csq/2); 4 broadcast copies (one per quad slot group).
  if (kt == 0) ((float*)tbase)[quad * 16 + m] = -1024.0f * s;

  _Float16* dst =
      (_Float16*)(tbase + 256 + (size_t)kt * 3072) + (quad * 16 + m) * 8;
  *(half8*)(dst) = hu;          // f=0 bh_u
  *(half8*)(dst + 512) = hs;    // f=1 bh_s
  *(half8*)(dst + 1024) = l8;   // f=2 bl'
}

// Block = 512 thr = 8 waves = 4 query-groups (64 q each) x 2 K-halves.
__global__ __launch_bounds__(512, 2) void vq_mfma(
    const float* __restrict__ z, const float4* __restrict__ cb4,
    const char* __restrict__ cbf, float4* __restrict__ out4) {
  __shared__ char sbuf[2][2][TILE_BYTES];  // [stream kh][dbuf]
  __shared__ float rv[2][256];
  __shared__ int rk[2][256];
  __shared__ int sidx[256];

  const int tid = threadIdx.x;
  const int lane = tid & 63;
  const int wave = tid >> 6;   // 0..7
  const int qg = wave & 3;     // query group (64 queries each)
  const int kh = wave >> 2;    // K half (32 tiles = 512 codes)
  const int m = lane & 15;
  const int quad = lane >> 4;

  // ---- staging-unit assignment: 14 units = stream(u/7) x item(u%7).
  // item 0 = c region (256 B, 16 active lanes); items 1..6 = 1 KB frags.
  const int u0 = wave;                    // units 0..7
  const int us0 = u0 / 7, ui0 = u0 % 7;
  const int uoff0 = (ui0 == 0) ? lane * 16
                               : 256 + (ui0 - 1) * 1024 + lane * 16;
  const bool act0 = (ui0 != 0) || (lane < 16);
  const bool has1 = (wave < 6);           // units 8..13
  const int us1 = (wave + 8) / 7, ui1 = (wave + 8) % 7;  // always a frag
  const int uoff1 = 256 + (ui1 - 1) * 1024 + lane * 16;

  float4 sr0, sr1;

  // --- prologue: issue stage(tile 0) so it flies under the A-build ---
  if (act0) sr0 = *(const float4*)(cbf + (size_t)(us0 * 32) * TILE_BYTES + uoff0);
  if (has1) sr1 = *(const float4*)(cbf + (size_t)(us1 * 32) * TILE_BYTES + uoff1);

  // --- A-fragments: 4 qtiles x 2 ktiles, h + l'. A[m][k=quad*8+j]. ---
  const int qbase = blockIdx.x * 256 + qg * 64;
  half8 ah[4][2], al[4][2];
#pragma unroll
  for (int qt = 0; qt < 4; ++qt) {
    const float* zr = z + (size_t)(qbase + qt * 16 + m) * DIM + quad * 8;
#pragma unroll
    for (int kt = 0; kt < 2; ++kt) {
      const float4 p0 = ((const float4*)(zr + kt * 32))[0];
      const float4 p1 = ((const float4*)(zr + kt * 32))[1];
      const float zf[8] = {p0.x, p0.y, p0.z, p0.w, p1.x, p1.y, p1.z, p1.w};
#pragma unroll
      for (int j = 0; j < 8; ++j) {
        const _Float16 h = (_Float16)zf[j];
        ah[qt][kt][j] = h;
        al[qt][kt][j] = (_Float16)((zf[j] - (float)h) * 2048.0f);
      }
    }
  }

  // --- write stage(0) into buf 0; make visible ---
  if (act0) *(float4*)&sbuf[us0][0][uoff0] = sr0;
  if (has1) *(float4*)&sbuf[us1][0][uoff1] = sr1;
  __syncthreads();

  const float4v zvec = {0.f, 0.f, 0.f, 0.f};
  float best[4][4];
  int bestt[4][4];
#pragma unroll
  for (int qt = 0; qt < 4; ++qt)
#pragma unroll
    for (int r = 0; r < 4; ++r) {
      best[qt][r] = -3.402823466e38f;
      bestt[qt][r] = 0;
    }

#pragma unroll 1
  for (int t = 0; t < 32; ++t) {
    // Issue stage(t+1) global loads (t=31 reads one tile past the stream:
    // stays inside the 256 MiB workspace, never consumed).
    const int tn = t + 1;
    if (act0) sr0 = *(const float4*)(cbf + (size_t)(us0 * 32 + tn) * TILE_BYTES + uoff0);
    if (has1) sr1 = *(const float4*)(cbf + (size_t)(us1 * 32 + tn) * TILE_BYTES + uoff1);

    // Compute tile t from LDS (stream kh).
    const char* mt = &sbuf[kh][t & 1][0];
    const float c = ((const float*)mt)[lane];
    const half8 hu0 = *(const half8*)(mt + 256 + lane * 16);
    const half8 hs0 = *(const half8*)(mt + 1280 + lane * 16);
    const half8 l0 = *(const half8*)(mt + 2304 + lane * 16);
    const half8 hu1 = *(const half8*)(mt + 3328 + lane * 16);
    const half8 hs1 = *(const half8*)(mt + 4352 + lane * 16);
    const half8 l1 = *(const half8*)(mt + 5376 + lane * 16);
    const float4v cvec = {c, c, c, c};

#pragma unroll
    for (int qt = 0; qt < 4; ++qt) {
      // Two independent 3-deep chains (kt0 seeded csq', kt1 seeded 0).
      float4v SA = __builtin_amdgcn_mfma_f32_16x16x32_f16(al[qt][0], hu0, cvec, 0, 0, 0);
      float4v SB = __builtin_amdgcn_mfma_f32_16x16x32_f16(al[qt][1], hu1, zvec, 0, 0, 0);
      SA = __builtin_amdgcn_mfma_f32_16x16x32_f16(ah[qt][0], l0, SA, 0, 0, 0);
      SB = __builtin_amdgcn_mfma_f32_16x16x32_f16(ah[qt][1], l1, SB, 0, 0, 0);
      SA = __builtin_amdgcn_mfma_f32_16x16x32_f16(ah[qt][0], hs0, SA, 0, 0, 0);
      SB = __builtin_amdgcn_mfma_f32_16x16x32_f16(ah[qt][1], hs1, SB, 0, 0, 0);
#pragma unroll
      for (int r = 0; r < 4; ++r) {
        const float v = SA[r] + SB[r];
        // t ascending per lane + strict > keeps lowest-k maximum.
        const bool gt = v > best[qt][r];
        best[qt][r] = fmaxf(v, best[qt][r]);
        bestt[qt][r] = gt ? t : bestt[qt][r];
      }
    }

    // Write stage(t+1) into the other buffer; barrier publishes it and
    // retires this iteration's reads of buf[t&1].
    const int b = tn & 1;
    if (act0) *(float4*)&sbuf[us0][b][uoff0] = sr0;
    if (has1) *(float4*)&sbuf[us1][b][uoff1] = sr1;
    __syncthreads();
  }

  // Cross-lane argmax over the 16 cols (m) in each quad; ties -> lower k.
  const int kbase = kh * 512 + m;
#pragma unroll
  for (int qt = 0; qt < 4; ++qt)
#pragma unroll
    for (int r = 0; r < 4; ++r) {
      float b = best[qt][r];
      int bk = kbase + bestt[qt][r] * 16;
#pragma unroll
      for (int s = 1; s < 16; s <<= 1) {
        const float ob = __shfl_xor(b, s);
        const int obk = __shfl_xor(bk, s);
        if (ob > b || (ob == b && obk < bk)) { b = ob; bk = obk; }
      }
      if (m == 0) {
        const int qb = qg * 64 + qt * 16 + quad * 4 + r;  // 0..255
        rv[kh][qb] = b;
        rk[kh][qb] = bk;
      }
    }
  __syncthreads();

  // Combine K-halves (strict >: ties -> half 0 = lower k).
  if (tid < 256) {
    const float v0 = rv[0][tid], v1 = rv[1][tid];
    sidx[tid] = (v1 > v0) ? rk[1][tid] : rk[0][tid];
  }
  __syncthreads();

  // Gather winning fp32 codebook rows; coalesced float4 writes.
  const size_t obase = (size_t)blockIdx.x * 256 * (DIM / 4);
#pragma unroll
  for (int f0 = 0; f0 < 256 * (DIM / 4); f0 += 512) {
    const int f = f0 + tid;
    const int q = f >> 4, e = f & 15;
    out4[obase + f] = cb4[(size_t)sidx[q] * (DIM / 4) + e];
  }
}

extern "C" void kernel_launch(void* const* d_in, const int* in_sizes, int n_in,
                              void* d_out, int out_size, void* d_ws, size_t ws_size,
                              hipStream_t stream) {
  const float* z = (const float*)d_in[0];
  const float* cb = (const float*)d_in[1];
  char* cbf = (char*)d_ws;  // 64 tiles x 6400 B = 400 KB

  const int nq = in_sizes[0] / DIM;  // 65536
  prep_kernel<<<(KCODES * 8) / 256, 256, 0, stream>>>(cb, cbf);
  vq_mfma<<<nq / 256, 512, 0, stream>>>(z, (const float4*)cb, cbf,
                                        (float4*)d_out);
}